// Round 12
// baseline (90.502 us; speedup 1.0000x reference)
//
#include <hip/hip_runtime.h>
#include <stdint.h>

// SSIM fused kernel v12, MI355X (gfx950).
// v11 post-mortem: WIN (93->87us). Padding never moved conflicts -> they're
// structural in staging (~8% LDS overhead, 2nd order). Occupancy pins ~39%
// regardless of allowed blocks/CU -> occupancy plays dead; work-per-output
// cuts pay. v12 amortizes the halo VERTICALLY:
//  - 64x32 output tile per 512-thread block: halo row-conv redundancy
//    26/16=1.63x -> 42/32=1.31x (stage-0/1 work x0.81); block count halved
//    (6144). LDS 57.8KB -> 2 blocks/CU x 8 waves = same 16 waves/CU.
//  - Per-thread structure preserved: 1 stage-1 item (8 cols), 4 stage-2
//    outputs. All proven pieces kept: f32 LDS staging, packed-f32 scatter
//    row conv, RTN fp16 rbAB + f32 rbC, packed stage-2, 2-kernel mean.

#define HH 512
#define WW 512
#define PLANES 48
#define TW 64
#define TH 32
#define RR 5
#define KK 11
#define IN_H (TH + 2 * RR)        // 42
#define SW 80                      // sp/st row stride (staged cols x0-8..x0+71)
#define NBLOCKS (PLANES * (WW / TW) * (HH / TH))  // 48*8*16 = 6144
#define NTHREADS 512
#define NSTAGE (IN_H * 20)        // 840 staging granules
#define NITEMS (IN_H * 8)         // 336 row-conv items (row, 8-col group)
#define TOTAL_ELEMS (PLANES * HH * WW)

typedef _Float16 half2v __attribute__((ext_vector_type(2)));
typedef float float2v __attribute__((ext_vector_type(2)));

constexpr float G_[KK] = {
    1.4867195147342977e-06f, 1.3383022576488537e-04f, 4.4318484119380075e-03f,
    5.3990966513188063e-02f, 2.4197072451914337e-01f, 3.9894228040143270e-01f,
    2.4197072451914337e-01f, 5.3990966513188063e-02f, 4.4318484119380075e-03f,
    1.3383022576488537e-04f, 1.4867195147342977e-06f};

__device__ __forceinline__ half2v u2h(uint32_t u) {
  return __builtin_bit_cast(half2v, u);
}
// RTN fp16 pack — unbiased (v4/v8 verified; RTZ pack is NOT safe, v7).
__device__ __forceinline__ uint32_t packrtn(float a, float b) {
  half2v h = {(_Float16)a, (_Float16)b};
  return __builtin_bit_cast(uint32_t, h);
}

__global__ __launch_bounds__(NTHREADS, 4) void ssim_tile_kernel(
    const float* __restrict__ pred, const float* __restrict__ targ,
    float* __restrict__ partial) {
  __shared__ __align__(16) float sp[IN_H][SW];    // 13.1 KB raw pred
  __shared__ __align__(16) float st[IN_H][SW];    // 13.1 KB raw targ
  __shared__ __align__(16) uint2 rbAB[IN_H][TW];  // 21.0 KB {pk(p,t),pk(pp,tt)}
  __shared__ __align__(16) float rbC[IN_H][TW];   // 10.5 KB conv_pt f32
  __shared__ float wsums[8];

  const int tid = threadIdx.x;
  const int bid = blockIdx.x;
  const int plane = bid >> 7;          // 128 tiles per plane
  const int tile = bid & 127;
  const int x0 = (tile & 7) * TW;
  const int y0 = (tile >> 3) * TH;     // 0..480 step 32
  const float* pp = pred + (size_t)plane * (HH * WW);
  const float* tp = targ + (size_t)plane * (HH * WW);

  // ---- Stage 0: stage raw halo (granule-aligned float4, uniform path) ----
  for (int i = tid; i < NSTAGE; i += NTHREADS) {
    const int r = i / 20;            // halo row 0..41
    const int cg = i - r * 20;       // granule 0..19
    const int gy = y0 + r - RR;
    const int gx = x0 - 8 + cg * 4;  // granule start, 16B aligned
    float4 pv = make_float4(0.f, 0.f, 0.f, 0.f);
    float4 tv = pv;
    if (gy >= 0 && gy < HH && gx >= 0 && gx <= WW - 4) {
      const int o = gy * WW + gx;
      pv = *reinterpret_cast<const float4*>(pp + o);
      tv = *reinterpret_cast<const float4*>(tp + o);
    }
    *reinterpret_cast<float4*>(&sp[r][cg * 4]) = pv;
    *reinterpret_cast<float4*>(&st[r][cg * 4]) = tv;
  }
  __syncthreads();

  // ---- Stage 1: row conv of 5 quantities, 8 outputs/thread, one shot ----
  if (tid < NITEMS) {
    const int r = tid >> 3;          // 0..41
    const int c8 = (tid & 7) << 3;   // 0..56 output col group base
    // staged window cols c8 .. c8+23 (global x0+c8-8 .. x0+c8+15)
    float pw[24], tw[24];
#pragma unroll
    for (int u = 0; u < 6; ++u) {
      float4 a = *reinterpret_cast<const float4*>(&sp[r][c8 + 4 * u]);
      float4 b = *reinterpret_cast<const float4*>(&st[r][c8 + 4 * u]);
      pw[4*u+0] = a.x; pw[4*u+1] = a.y; pw[4*u+2] = a.z; pw[4*u+3] = a.w;
      tw[4*u+0] = b.x; tw[4*u+1] = b.y; tw[4*u+2] = b.z; tw[4*u+3] = b.w;
    }

    // Scatter form, packed f32. Window position q (3..20) contributes to
    // outputs j in [q-13, q-3] ∩ [0,7] with weight G_[q-3-j].
    float2v s01[8] = {{0,0},{0,0},{0,0},{0,0},{0,0},{0,0},{0,0},{0,0}};
    float2v s23[8] = {{0,0},{0,0},{0,0},{0,0},{0,0},{0,0},{0,0},{0,0}};
    float s4[8] = {0,0,0,0,0,0,0,0};
#pragma unroll
    for (int q = 3; q <= 20; ++q) {
      const float a = pw[q];
      const float b = tw[q];
      const float2v av = {a, b};
      const float2v sq = av * av;      // v_pk_mul_f32
      const float ab = a * b;
#pragma unroll
      for (int j = 0; j < 8; ++j) {
        if (j < q - 13 || j > q - 3) continue;
        const float w = G_[q - 3 - j];
        const float2v w2 = {w, w};
        s01[j] = __builtin_elementwise_fma(w2, av, s01[j]);  // v_pk_fma_f32
        s23[j] = __builtin_elementwise_fma(w2, sq, s23[j]);
        s4[j] = fmaf(w, ab, s4[j]);
      }
    }

#pragma unroll
    for (int h = 0; h < 4; ++h) {    // 4 x uint4 = cols c8..c8+7
      uint4 wv;
      wv.x = packrtn(s01[2*h].x,   s01[2*h].y);
      wv.y = packrtn(s23[2*h].x,   s23[2*h].y);
      wv.z = packrtn(s01[2*h+1].x, s01[2*h+1].y);
      wv.w = packrtn(s23[2*h+1].x, s23[2*h+1].y);
      *reinterpret_cast<uint4*>(&rbAB[r][c8 + 2*h]) = wv;
    }
    *reinterpret_cast<float4*>(&rbC[r][c8]) =
        make_float4(s4[0], s4[1], s4[2], s4[3]);
    *reinterpret_cast<float4*>(&rbC[r][c8 + 4]) =
        make_float4(s4[4], s4[5], s4[6], s4[7]);
  }
  __syncthreads();

  // ---- Stage 2: column conv (packed f32) + SSIM map ----
  float lsum = 0.f;
  {
    const int x = tid & 63;
    const int ybase = (tid >> 6) * 4;  // 0,4,...,28
    float2v fa[14], fb[14];
    float vc[14];
#pragma unroll
    for (int m = 0; m < 14; ++m) {
      uint2 q = rbAB[ybase + m][x];    // ds_read_b64
      half2v ha = u2h(q.x), hb = u2h(q.y);
      fa[m] = float2v{(float)ha.x, (float)ha.y};
      fb[m] = float2v{(float)hb.x, (float)hb.y};
      vc[m] = rbC[ybase + m][x];
    }

    float2v accA[4], accB[4];
    float sC[4];
#pragma unroll
    for (int j = 0; j < 4; ++j) {
      float2v a = {0, 0}, b = {0, 0};
      float c = 0.f;
#pragma unroll
      for (int k = 0; k < KK; ++k) {
        const float2v w2 = {G_[k], G_[k]};
        a = __builtin_elementwise_fma(w2, fa[j + k], a);
        b = __builtin_elementwise_fma(w2, fb[j + k], b);
        c = fmaf(G_[k], vc[j + k], c);
      }
      accA[j] = a; accB[j] = b; sC[j] = c;
    }

    const float C1 = 1.0e-4f;
    const float C2 = 9.0e-4f;
#pragma unroll
    for (int j = 0; j < 4; ++j) {
      const float mu_x = accA[j].x;
      const float mu_y = accA[j].y;
      // {sxx, syy} = accB - accA*accA in one pk_fma (neg modifier)
      const float2v sv = __builtin_elementwise_fma(-accA[j], accA[j], accB[j]);
      const float sxy = sC[j] - mu_x * mu_y;
      const float num = (2.f * mu_x * mu_y + C1) * (2.f * sxy + C2);
      const float den = (mu_x * mu_x + mu_y * mu_y + C1) *
                        (fmaf(sv.x, sv.x, fmaf(sv.y, sv.y, C2)));
      lsum = fmaf(num, __builtin_amdgcn_rcpf(den), lsum);
    }
  }

  // ---- Block reduction -> partial[bid] ----
#pragma unroll
  for (int off = 32; off > 0; off >>= 1) lsum += __shfl_xor(lsum, off, 64);
  if ((tid & 63) == 0) wsums[tid >> 6] = lsum;
  __syncthreads();
  if (tid == 0) {
    float s = 0.f;
#pragma unroll
    for (int w = 0; w < 8; ++w) s += wsums[w];
    partial[bid] = s;
  }
}

__global__ __launch_bounds__(1024) void ssim_reduce_kernel(
    const float* __restrict__ partial, float* __restrict__ out) {
  float s = 0.f;
  for (int i = threadIdx.x; i < NBLOCKS; i += 1024) s += partial[i];
#pragma unroll
  for (int off = 32; off > 0; off >>= 1) s += __shfl_xor(s, off, 64);
  __shared__ float ws[16];
  if ((threadIdx.x & 63) == 0) ws[threadIdx.x >> 6] = s;
  __syncthreads();
  if (threadIdx.x == 0) {
    float t = 0.f;
#pragma unroll
    for (int i = 0; i < 16; ++i) t += ws[i];
    out[0] = t * (1.0f / (float)TOTAL_ELEMS);
  }
}

extern "C" void kernel_launch(void* const* d_in, const int* in_sizes, int n_in,
                              void* d_out, int out_size, void* d_ws,
                              size_t ws_size, hipStream_t stream) {
  const float* pred = (const float*)d_in[0];
  const float* targ = (const float*)d_in[1];
  float* out = (float*)d_out;
  float* partial = (float*)d_ws;  // 6144 * 4 = 24 KiB of d_ws

  ssim_tile_kernel<<<NBLOCKS, NTHREADS, 0, stream>>>(pred, targ, partial);
  ssim_reduce_kernel<<<1, 1024, 0, stream>>>(partial, out);
}

// Round 13
// 78.727 us; speedup vs baseline: 1.1496x; 1.1496x over previous
//
#include <hip/hip_runtime.h>
#include <stdint.h>

// SSIM fused kernel v13, MI355X (gfx950).
// v12 (64x32 tile) regressed: 2 blocks/CU -> weaker barrier-latency hiding,
// conflicts up. Reverted to v11 base (64x16, 256 thr, 4 blk/CU).
// v13 attacks the now-QUANTIFIED conflicts (model matched 1180/block):
//  - Stage-1 item mapping transposed: consecutive lanes take consecutive ROWS
//    (r = 8*wave + (lane&7), m = (lane>>3)&7). With SW=84 (20r mod 32 spans
//    all multiples of 4), each 8-lane b128 group covers all 32 banks ->
//    stage-1 sp/st reads conflict-free (was 2-way on every read).
//  - rbAB stride 64->66 uint2 (132 words = 4 mod 32), rbC 64->68 floats:
//    stage-1 writes conflict-free (was 4-way rbAB / 2-way rbC);
//    stage-2 reads stay conflict-free (b64 quarter-wave spans 32 banks;
//    b32 2 lanes/bank = free).
// All else = v11: f32 LDS staging, packed-f32 scatter row conv, RTN fp16
// rbAB + f32 rbC, packed stage-2, 2-kernel deterministic mean.

#define HH 512
#define WW 512
#define PLANES 48
#define TW 64
#define TH 16
#define RR 5
#define KK 11
#define IN_H (TH + 2 * RR)        // 26
#define SW 84                      // sp/st row stride (80 staged cols used)
#define RBW 66                     // rbAB row stride (uint2), = 4 mod 32 words
#define RCW 68                     // rbC row stride (float), = 4 mod 32 words
#define NBLOCKS (PLANES * (WW / TW) * (HH / TH))  // 12288
#define NTHREADS 256
#define NSTAGE (IN_H * 20)        // 520 staging granules
#define TOTAL_ELEMS (PLANES * HH * WW)

typedef _Float16 half2v __attribute__((ext_vector_type(2)));
typedef float float2v __attribute__((ext_vector_type(2)));

constexpr float G_[KK] = {
    1.4867195147342977e-06f, 1.3383022576488537e-04f, 4.4318484119380075e-03f,
    5.3990966513188063e-02f, 2.4197072451914337e-01f, 3.9894228040143270e-01f,
    2.4197072451914337e-01f, 5.3990966513188063e-02f, 4.4318484119380075e-03f,
    1.3383022576488537e-04f, 1.4867195147342977e-06f};

__device__ __forceinline__ half2v u2h(uint32_t u) {
  return __builtin_bit_cast(half2v, u);
}
// RTN fp16 pack — unbiased (v4/v8 verified; RTZ pack is NOT safe, v7).
__device__ __forceinline__ uint32_t packrtn(float a, float b) {
  half2v h = {(_Float16)a, (_Float16)b};
  return __builtin_bit_cast(uint32_t, h);
}

__global__ __launch_bounds__(NTHREADS, 4) void ssim_tile_kernel(
    const float* __restrict__ pred, const float* __restrict__ targ,
    float* __restrict__ partial) {
  __shared__ __align__(16) float sp[IN_H][SW];     // 8.7 KB raw pred
  __shared__ __align__(16) float st[IN_H][SW];     // 8.7 KB raw targ
  __shared__ __align__(16) uint2 rbAB[IN_H][RBW];  // 13.7 KB {pk(p,t),pk(pp,tt)}
  __shared__ __align__(16) float rbC[IN_H][RCW];   // 7.1 KB conv_pt f32
  __shared__ float wsums[4];

  const int tid = threadIdx.x;
  const int bid = blockIdx.x;
  const int plane = bid >> 8;
  const int tile = bid & 255;
  const int x0 = (tile & 7) * TW;
  const int y0 = (tile >> 3) * TH;
  const float* pp = pred + (size_t)plane * (HH * WW);
  const float* tp = targ + (size_t)plane * (HH * WW);

  // ---- Stage 0: stage raw halo (granule-aligned float4, uniform path) ----
  for (int i = tid; i < NSTAGE; i += NTHREADS) {
    const int r = i / 20;            // halo row 0..25
    const int cg = i - r * 20;       // granule 0..19
    const int gy = y0 + r - RR;
    const int gx = x0 - 8 + cg * 4;  // granule start, 16B aligned
    float4 pv = make_float4(0.f, 0.f, 0.f, 0.f);
    float4 tv = pv;
    if (gy >= 0 && gy < HH && gx >= 0 && gx <= WW - 4) {
      const int o = gy * WW + gx;
      pv = *reinterpret_cast<const float4*>(pp + o);
      tv = *reinterpret_cast<const float4*>(tp + o);
    }
    *reinterpret_cast<float4*>(&sp[r][cg * 4]) = pv;
    *reinterpret_cast<float4*>(&st[r][cg * 4]) = tv;
  }
  __syncthreads();

  // ---- Stage 1: row conv, 8 outputs/thread, lane<->row transposed map ----
  {
    const int l = tid & 63;
    const int r = 8 * (tid >> 6) + (l & 7);  // consecutive lanes -> rows
    const int m = (l >> 3);                  // col-group 0..7
    if (r < IN_H) {
      const int c8 = m << 3;
      // staged window cols c8 .. c8+23 (global x0+c8-8 .. x0+c8+15)
      float pw[24], tw[24];
#pragma unroll
      for (int u = 0; u < 6; ++u) {
        float4 a = *reinterpret_cast<const float4*>(&sp[r][c8 + 4 * u]);
        float4 b = *reinterpret_cast<const float4*>(&st[r][c8 + 4 * u]);
        pw[4*u+0] = a.x; pw[4*u+1] = a.y; pw[4*u+2] = a.z; pw[4*u+3] = a.w;
        tw[4*u+0] = b.x; tw[4*u+1] = b.y; tw[4*u+2] = b.z; tw[4*u+3] = b.w;
      }

      // Scatter form, packed f32. Window position q (3..20) contributes to
      // outputs j in [q-13, q-3] ∩ [0,7] with weight G_[q-3-j].
      float2v s01[8] = {{0,0},{0,0},{0,0},{0,0},{0,0},{0,0},{0,0},{0,0}};
      float2v s23[8] = {{0,0},{0,0},{0,0},{0,0},{0,0},{0,0},{0,0},{0,0}};
      float s4[8] = {0,0,0,0,0,0,0,0};
#pragma unroll
      for (int q = 3; q <= 20; ++q) {
        const float a = pw[q];
        const float b = tw[q];
        const float2v av = {a, b};
        const float2v sq = av * av;      // v_pk_mul_f32
        const float ab = a * b;
#pragma unroll
        for (int j = 0; j < 8; ++j) {
          if (j < q - 13 || j > q - 3) continue;
          const float w = G_[q - 3 - j];
          const float2v w2 = {w, w};
          s01[j] = __builtin_elementwise_fma(w2, av, s01[j]);  // v_pk_fma_f32
          s23[j] = __builtin_elementwise_fma(w2, sq, s23[j]);
          s4[j] = fmaf(w, ab, s4[j]);
        }
      }

#pragma unroll
      for (int h = 0; h < 4; ++h) {    // 4 x uint4 = cols c8..c8+7
        uint4 wv;
        wv.x = packrtn(s01[2*h].x,   s01[2*h].y);
        wv.y = packrtn(s23[2*h].x,   s23[2*h].y);
        wv.z = packrtn(s01[2*h+1].x, s01[2*h+1].y);
        wv.w = packrtn(s23[2*h+1].x, s23[2*h+1].y);
        *reinterpret_cast<uint4*>(&rbAB[r][c8 + 2*h]) = wv;
      }
      *reinterpret_cast<float4*>(&rbC[r][c8]) =
          make_float4(s4[0], s4[1], s4[2], s4[3]);
      *reinterpret_cast<float4*>(&rbC[r][c8 + 4]) =
          make_float4(s4[4], s4[5], s4[6], s4[7]);
    }
  }
  __syncthreads();

  // ---- Stage 2: column conv (packed f32) + SSIM map ----
  float lsum = 0.f;
  {
    const int x = tid & 63;
    const int ybase = (tid >> 6) * 4;  // 0,4,8,12
    float2v fa[14], fb[14];
    float vc[14];
#pragma unroll
    for (int m = 0; m < 14; ++m) {
      uint2 q = rbAB[ybase + m][x];    // ds_read_b64
      half2v ha = u2h(q.x), hb = u2h(q.y);
      fa[m] = float2v{(float)ha.x, (float)ha.y};
      fb[m] = float2v{(float)hb.x, (float)hb.y};
      vc[m] = rbC[ybase + m][x];
    }

    float2v accA[4], accB[4];
    float sC[4];
#pragma unroll
    for (int j = 0; j < 4; ++j) {
      float2v a = {0, 0}, b = {0, 0};
      float c = 0.f;
#pragma unroll
      for (int k = 0; k < KK; ++k) {
        const float2v w2 = {G_[k], G_[k]};
        a = __builtin_elementwise_fma(w2, fa[j + k], a);
        b = __builtin_elementwise_fma(w2, fb[j + k], b);
        c = fmaf(G_[k], vc[j + k], c);
      }
      accA[j] = a; accB[j] = b; sC[j] = c;
    }

    const float C1 = 1.0e-4f;
    const float C2 = 9.0e-4f;
#pragma unroll
    for (int j = 0; j < 4; ++j) {
      const float mu_x = accA[j].x;
      const float mu_y = accA[j].y;
      // {sxx, syy} = accB - accA*accA in one pk_fma (neg modifier)
      const float2v sv = __builtin_elementwise_fma(-accA[j], accA[j], accB[j]);
      const float sxy = sC[j] - mu_x * mu_y;
      const float num = (2.f * mu_x * mu_y + C1) * (2.f * sxy + C2);
      const float den = (mu_x * mu_x + mu_y * mu_y + C1) *
                        (fmaf(sv.x, sv.x, fmaf(sv.y, sv.y, C2)));
      lsum = fmaf(num, __builtin_amdgcn_rcpf(den), lsum);
    }
  }

  // ---- Block reduction -> partial[bid] ----
#pragma unroll
  for (int off = 32; off > 0; off >>= 1) lsum += __shfl_xor(lsum, off, 64);
  if ((tid & 63) == 0) wsums[tid >> 6] = lsum;
  __syncthreads();
  if (tid == 0)
    partial[bid] = (wsums[0] + wsums[1]) + (wsums[2] + wsums[3]);
}

__global__ __launch_bounds__(1024) void ssim_reduce_kernel(
    const float* __restrict__ partial, float* __restrict__ out) {
  float s = 0.f;
  for (int i = threadIdx.x; i < NBLOCKS; i += 1024) s += partial[i];
#pragma unroll
  for (int off = 32; off > 0; off >>= 1) s += __shfl_xor(s, off, 64);
  __shared__ float ws[16];
  if ((threadIdx.x & 63) == 0) ws[threadIdx.x >> 6] = s;
  __syncthreads();
  if (threadIdx.x == 0) {
    float t = 0.f;
#pragma unroll
    for (int i = 0; i < 16; ++i) t += ws[i];
    out[0] = t * (1.0f / (float)TOTAL_ELEMS);
  }
}

extern "C" void kernel_launch(void* const* d_in, const int* in_sizes, int n_in,
                              void* d_out, int out_size, void* d_ws,
                              size_t ws_size, hipStream_t stream) {
  const float* pred = (const float*)d_in[0];
  const float* targ = (const float*)d_in[1];
  float* out = (float*)d_out;
  float* partial = (float*)d_ws;

  ssim_tile_kernel<<<NBLOCKS, NTHREADS, 0, stream>>>(pred, targ, partial);
  ssim_reduce_kernel<<<1, 1024, 0, stream>>>(partial, out);
}

// Round 14
// 69.927 us; speedup vs baseline: 1.2942x; 1.1258x over previous
//
#include <hip/hip_runtime.h>
#include <stdint.h>

// SSIM fused kernel v14, MI355X (gfx950).
// v13 post-mortem: WIN (87->84.5us, conflicts -35%). VALU-issue bound.
// v14: COLUMN-FIRST separable order. First pass = vertical conv: 74x16
// outputs (halo redundancy 1.16x) instead of row-first 26x64 (1.63x) ->
// 0.71x first-pass work. Both passes boundary-free (zero-padded halo does
// it all). Second pass reads contiguous horizontal windows: 11 b128 per
// thread (vs 28 DS ops), 16B-aligned at every 4-col group; residual read
// aliasing is 2-way = free (m136). First-pass accesses conflict-free by
// construction (consecutive lanes -> consecutive cols).
// Kept: stage-0 f32 staging (SW=84), packed-f32 (v_pk_fma_f32) conv math,
// RTN fp16 rbAB storage + f32 rbC (pt), 2-kernel deterministic mean.

#define HH 512
#define WW 512
#define PLANES 48
#define TW 64
#define TH 16
#define RR 5
#define KK 11
#define IN_H (TH + 2 * RR)        // 26 halo rows
#define HALO_W 74                  // halo cols used (x0-5 .. x0+68)
#define SW 84                      // sp/st row stride (staged x0-8..x0+71 at +0..79)
#define COFF 3                     // halo col c -> staged col c+3
#define RBW 76                     // rb row stride
#define NBLOCKS (PLANES * (WW / TW) * (HH / TH))  // 12288
#define NTHREADS 256
#define NSTAGE (IN_H * 20)        // 520 staging granules
#define NITEMS1 (HALO_W * 4)      // 296 first-pass items (col, 4-row group)
#define TOTAL_ELEMS (PLANES * HH * WW)

typedef _Float16 half2v __attribute__((ext_vector_type(2)));
typedef float float2v __attribute__((ext_vector_type(2)));

constexpr float G_[KK] = {
    1.4867195147342977e-06f, 1.3383022576488537e-04f, 4.4318484119380075e-03f,
    5.3990966513188063e-02f, 2.4197072451914337e-01f, 3.9894228040143270e-01f,
    2.4197072451914337e-01f, 5.3990966513188063e-02f, 4.4318484119380075e-03f,
    1.3383022576488537e-04f, 1.4867195147342977e-06f};

__device__ __forceinline__ half2v u2h(uint32_t u) {
  return __builtin_bit_cast(half2v, u);
}
// RTN fp16 pack — unbiased (v4/v8 verified; RTZ pack is NOT safe, v7).
__device__ __forceinline__ uint32_t packrtn(float a, float b) {
  half2v h = {(_Float16)a, (_Float16)b};
  return __builtin_bit_cast(uint32_t, h);
}

__global__ __launch_bounds__(NTHREADS, 4) void ssim_tile_kernel(
    const float* __restrict__ pred, const float* __restrict__ targ,
    float* __restrict__ partial) {
  __shared__ __align__(16) float sp[IN_H][SW];     // 8.7 KB raw pred
  __shared__ __align__(16) float st[IN_H][SW];     // 8.7 KB raw targ
  __shared__ __align__(16) uint2 rbAB[TH][RBW];    // 9.5 KB {pk(p,t),pk(pp,tt)}
  __shared__ __align__(16) float rbC[TH][RBW];     // 4.75 KB vconv_pt f32
  __shared__ float wsums[4];

  const int tid = threadIdx.x;
  const int bid = blockIdx.x;
  const int plane = bid >> 8;
  const int tile = bid & 255;
  const int x0 = (tile & 7) * TW;
  const int y0 = (tile >> 3) * TH;
  const float* pp = pred + (size_t)plane * (HH * WW);
  const float* tp = targ + (size_t)plane * (HH * WW);

  // ---- Stage 0: stage raw halo (granule-aligned float4, uniform path) ----
  for (int i = tid; i < NSTAGE; i += NTHREADS) {
    const int r = i / 20;            // halo row 0..25
    const int cg = i - r * 20;       // granule 0..19
    const int gy = y0 + r - RR;
    const int gx = x0 - 8 + cg * 4;  // granule start, 16B aligned
    float4 pv = make_float4(0.f, 0.f, 0.f, 0.f);
    float4 tv = pv;
    if (gy >= 0 && gy < HH && gx >= 0 && gx <= WW - 4) {
      const int o = gy * WW + gx;
      pv = *reinterpret_cast<const float4*>(pp + o);
      tv = *reinterpret_cast<const float4*>(tp + o);
    }
    *reinterpret_cast<float4*>(&sp[r][cg * 4]) = pv;
    *reinterpret_cast<float4*>(&st[r][cg * 4]) = tv;
  }
  __syncthreads();

  // ---- Pass 1: VERTICAL conv of 5 quantities; items = (halo col, 4 rows) --
  for (int i = tid; i < NITEMS1; i += NTHREADS) {
    const int c = i % HALO_W;        // halo col 0..73
    const int rg = i / HALO_W;       // 0..3
    const int yb = rg * 4;           // output rows yb..yb+3
    const int sc = c + COFF;         // staged col

    float pv[14], tv[14];
#pragma unroll
    for (int m = 0; m < 14; ++m) {
      pv[m] = sp[yb + m][sc];
      tv[m] = st[yb + m][sc];
    }

    // Scatter: input row-position q (0..13) feeds outputs j in
    // [max(0,q-10), min(3,q)] with weight G_[q-j].
    float2v s01[4] = {{0,0},{0,0},{0,0},{0,0}};
    float2v s23[4] = {{0,0},{0,0},{0,0},{0,0}};
    float s4[4] = {0,0,0,0};
#pragma unroll
    for (int q = 0; q < 14; ++q) {
      const float a = pv[q];
      const float b = tv[q];
      const float2v av = {a, b};
      const float2v sq = av * av;      // v_pk_mul_f32
      const float ab = a * b;
#pragma unroll
      for (int j = 0; j < 4; ++j) {
        if (q < j || q > j + 10) continue;
        const float w = G_[q - j];
        const float2v w2 = {w, w};
        s01[j] = __builtin_elementwise_fma(w2, av, s01[j]);  // v_pk_fma_f32
        s23[j] = __builtin_elementwise_fma(w2, sq, s23[j]);
        s4[j] = fmaf(w, ab, s4[j]);
      }
    }

#pragma unroll
    for (int j = 0; j < 4; ++j) {
      uint2 u;
      u.x = packrtn(s01[j].x, s01[j].y);
      u.y = packrtn(s23[j].x, s23[j].y);
      rbAB[yb + j][c] = u;             // ds_write_b64, lanes->cols: clean
      rbC[yb + j][c] = s4[j];          // ds_write_b32: clean
    }
  }
  __syncthreads();

  // ---- Pass 2: HORIZONTAL conv (packed f32) + SSIM map; 256 items exact --
  float lsum = 0.f;
  {
    const int m = tid & 15;          // col group 0..15
    const int y = tid >> 4;          // output row 0..15
    const int cb = m << 2;           // window cols cb..cb+13 (outputs cb..cb+3)

    // contiguous window reads: 7 b128 (rbAB) + 4 b128 (rbC, 2 tail unused)
    uint2 qv[14];
#pragma unroll
    for (int h = 0; h < 7; ++h) {
      uint4 w = *reinterpret_cast<const uint4*>(&rbAB[y][cb + 2 * h]);
      qv[2*h]   = make_uint2(w.x, w.y);
      qv[2*h+1] = make_uint2(w.z, w.w);
    }
    float cv[16];
#pragma unroll
    for (int h = 0; h < 4; ++h) {
      *reinterpret_cast<float4*>(&cv[4*h]) =
          *reinterpret_cast<const float4*>(&rbC[y][cb + 4 * h]);
    }

    float2v fa[14], fb[14];
#pragma unroll
    for (int k = 0; k < 14; ++k) {
      half2v ha = u2h(qv[k].x), hb = u2h(qv[k].y);
      fa[k] = float2v{(float)ha.x, (float)ha.y};
      fb[k] = float2v{(float)hb.x, (float)hb.y};
    }

    float2v accA[4], accB[4];
    float sC[4];
#pragma unroll
    for (int j = 0; j < 4; ++j) {
      float2v a = {0, 0}, b = {0, 0};
      float c = 0.f;
#pragma unroll
      for (int k = 0; k < KK; ++k) {
        const float2v w2 = {G_[k], G_[k]};
        a = __builtin_elementwise_fma(w2, fa[j + k], a);
        b = __builtin_elementwise_fma(w2, fb[j + k], b);
        c = fmaf(G_[k], cv[j + k], c);
      }
      accA[j] = a; accB[j] = b; sC[j] = c;
    }

    const float C1 = 1.0e-4f;
    const float C2 = 9.0e-4f;
#pragma unroll
    for (int j = 0; j < 4; ++j) {
      const float mu_x = accA[j].x;
      const float mu_y = accA[j].y;
      const float2v sv = __builtin_elementwise_fma(-accA[j], accA[j], accB[j]);
      const float sxy = sC[j] - mu_x * mu_y;
      const float num = (2.f * mu_x * mu_y + C1) * (2.f * sxy + C2);
      const float den = (mu_x * mu_x + mu_y * mu_y + C1) *
                        (fmaf(sv.x, sv.x, fmaf(sv.y, sv.y, C2)));
      lsum = fmaf(num, __builtin_amdgcn_rcpf(den), lsum);
    }
  }

  // ---- Block reduction -> partial[bid] ----
#pragma unroll
  for (int off = 32; off > 0; off >>= 1) lsum += __shfl_xor(lsum, off, 64);
  if ((tid & 63) == 0) wsums[tid >> 6] = lsum;
  __syncthreads();
  if (tid == 0)
    partial[bid] = (wsums[0] + wsums[1]) + (wsums[2] + wsums[3]);
}

__global__ __launch_bounds__(1024) void ssim_reduce_kernel(
    const float* __restrict__ partial, float* __restrict__ out) {
  float s = 0.f;
  for (int i = threadIdx.x; i < NBLOCKS; i += 1024) s += partial[i];
#pragma unroll
  for (int off = 32; off > 0; off >>= 1) s += __shfl_xor(s, off, 64);
  __shared__ float ws[16];
  if ((threadIdx.x & 63) == 0) ws[threadIdx.x >> 6] = s;
  __syncthreads();
  if (threadIdx.x == 0) {
    float t = 0.f;
#pragma unroll
    for (int i = 0; i < 16; ++i) t += ws[i];
    out[0] = t * (1.0f / (float)TOTAL_ELEMS);
  }
}

extern "C" void kernel_launch(void* const* d_in, const int* in_sizes, int n_in,
                              void* d_out, int out_size, void* d_ws,
                              size_t ws_size, hipStream_t stream) {
  const float* pred = (const float*)d_in[0];
  const float* targ = (const float*)d_in[1];
  float* out = (float*)d_out;
  float* partial = (float*)d_ws;

  ssim_tile_kernel<<<NBLOCKS, NTHREADS, 0, stream>>>(pred, targ, partial);
  ssim_reduce_kernel<<<1, 1024, 0, stream>>>(partial, out);
}